// Round 9
// baseline (55023.157 us; speedup 1.0000x reference)
//
#include <hip/hip_runtime.h>
#include <hip/hip_bf16.h>

#define T_DIM 8192
#define O_DIM 1024
#define H_DIM 2048
#define G_DIM 6144   // 3*H
#define A_DIM 512
#define CHUNK 512    // steps per scan launch
#define NBLK 256     // scan blocks (1 per CU; forced by dummy LDS)

// ---- workspace layout (float offsets; total ~46.7 MB, proven safe) ----
#define OFF_GXC   0ull          // CHUNK x 3H fp32            (3,145,728 f)
#define OFF_HTAG  3145728ull    // 2 x H u64 {h,tag}          (8,192 f)
#define OFF_S     3153920ull    // 8192 scores fp32
#define OFF_RED   3162112ull    // max, sum (+pad)            (16 f)
#define OFF_CPART 3162128ull    // 64 x 2048 fp32             (131,072 f)
#define OFF_C     3293200ull    // 2048 fp32
#define OFF_HSBF  3295248ull    // T x H bf16                 (8,388,608 f)

__device__ __forceinline__ float bf2f(unsigned short u) {
  return __uint_as_float(((unsigned)u) << 16);
}

// ---------------- Phase 1: gx chunk = obs_chunk @ W_ih^T + b_ih ----------------
#define BM 64
#define BN 64
#define BK 16
__global__ __launch_bounds__(256) void gemm_gx(
    const float* __restrict__ A,   // CHUNK x O
    const float* __restrict__ B,   // 3H x O
    const float* __restrict__ bias,
    float* __restrict__ C) {       // CHUNK x 3H
  __shared__ float As[BM][BK + 1];
  __shared__ float Bs[BN][BK + 1];
  const int bm = blockIdx.x * BM;
  const int bn = blockIdx.y * BN;
  const int tid = threadIdx.x;
  const int tr = tid / 16, tc = tid % 16;
  float acc[4][4] = {};
  for (int k0 = 0; k0 < O_DIM; k0 += BK) {
    for (int i = tid; i < BM * BK; i += 256) {
      int r = i / BK, c = i % BK;
      As[r][c] = A[(size_t)(bm + r) * O_DIM + k0 + c];
    }
    for (int i = tid; i < BN * BK; i += 256) {
      int r = i / BK, c = i % BK;
      Bs[r][c] = B[(size_t)(bn + r) * O_DIM + k0 + c];
    }
    __syncthreads();
#pragma unroll
    for (int kk = 0; kk < BK; ++kk) {
      float a[4], b[4];
#pragma unroll
      for (int i = 0; i < 4; ++i) a[i] = As[tr * 4 + i][kk];
#pragma unroll
      for (int j = 0; j < 4; ++j) b[j] = Bs[tc * 4 + j][kk];
#pragma unroll
      for (int i = 0; i < 4; ++i)
#pragma unroll
        for (int j = 0; j < 4; ++j) acc[i][j] += a[i] * b[j];
    }
    __syncthreads();
  }
#pragma unroll
  for (int i = 0; i < 4; ++i)
#pragma unroll
    for (int j = 0; j < 4; ++j) {
      int r = bm + tr * 4 + i, cc = bn + tc * 4 + j;
      C[(size_t)r * G_DIM + cc] = acc[i][j] + bias[cc];
    }
}

// one 4-wide FMA triple against named weight registers
#define DOT4(W0, W1, W2, IDX)                                        \
  do {                                                               \
    const float4 hh = h4[(IDX)];                                     \
    a0 += (W0).x * hh.x + (W0).y * hh.y + (W0).z * hh.z + (W0).w * hh.w; \
    a1 += (W1).x * hh.x + (W1).y * hh.y + (W1).z * hh.z + (W1).w * hh.w; \
    a2 += (W2).x * hh.x + (W2).y * hh.y + (W2).z * hh.z + (W2).w * hh.w; \
  } while (0)

// pin 12 floats into VGPRs: asm-produced values cannot be rematerialized
#define PIN12(a,b,c,d,e,f,g,h,i,j,k,l)                               \
  asm volatile("" : "+v"(a), "+v"(b), "+v"(c), "+v"(d), "+v"(e),     \
                    "+v"(f), "+v"(g), "+v"(h), "+v"(i), "+v"(j),     \
                    "+v"(k), "+v"(l))
#define PINV4(A, B, C)                                               \
  PIN12((A).x, (A).y, (A).z, (A).w, (B).x, (B).y, (B).z, (B).w,      \
        (C).x, (C).y, (C).z, (C).w)

// ---------------- Phase 2: persistent GRU scan -------------------------------
// 256 blocks x 512 threads (8 waves). Wave wv owns unit u = blk*8+wv; its 3
// W_hh rows live in 24 float4 VGPR values, ASM-PINNED so the compiler cannot
// rematerialize them as per-step loads (rounds 7/8: VGPR_Count=88 => weights
// were re-streamed from L2/L3 every step, FETCH 203MB/dispatch). Cross-block
// exchange via poll-the-data u64 {f32 h | u32 tag} at agent scope (IF-served,
// fence-free). Dummy LDS forces 1 block/CU.
__global__ __launch_bounds__(512, 1) void scan_chunk(
    const float* __restrict__ W_hh,        // 3H x H fp32
    const float* __restrict__ b_hh,        // 3H
    const float* __restrict__ gxc,         // CHUNK x 3H
    unsigned long long* __restrict__ htag, // 2 x H {h,tag}
    unsigned short* __restrict__ hsbf16,   // T x H bf16
    int t0, int nsteps) {
  __shared__ char smem[98304];             // 96 KB: 2 h-buffers + exclusivity pad
  float* hbuf0 = (float*)smem;             // H_DIM floats
  float* hbuf1 = (float*)(smem + 32768);   // H_DIM floats (16KB spacing)
  const int tid = threadIdx.x;
  const int lane = tid & 63;
  const int wv = tid >> 6;                 // wave 0..7
  const int blk = blockIdx.x;
  const int u = blk * 8 + wv;              // owned unit

  // ---- weights to 24 float4 registers (once per launch), fp32, asm-pinned ----
  const float4* wr0 = (const float4*)(W_hh + (size_t)(0 * H_DIM + u) * H_DIM);
  const float4* wr1 = (const float4*)(W_hh + (size_t)(1 * H_DIM + u) * H_DIM);
  const float4* wr2 = (const float4*)(W_hh + (size_t)(2 * H_DIM + u) * H_DIM);
  float4 w00 = wr0[lane +   0], w01 = wr0[lane +  64],
         w02 = wr0[lane + 128], w03 = wr0[lane + 192],
         w04 = wr0[lane + 256], w05 = wr0[lane + 320],
         w06 = wr0[lane + 384], w07 = wr0[lane + 448];
  float4 w10 = wr1[lane +   0], w11 = wr1[lane +  64],
         w12 = wr1[lane + 128], w13 = wr1[lane + 192],
         w14 = wr1[lane + 256], w15 = wr1[lane + 320],
         w16 = wr1[lane + 384], w17 = wr1[lane + 448];
  float4 w20 = wr2[lane +   0], w21 = wr2[lane +  64],
         w22 = wr2[lane + 128], w23 = wr2[lane + 192],
         w24 = wr2[lane + 256], w25 = wr2[lane + 320],
         w26 = wr2[lane + 384], w27 = wr2[lane + 448];
  PINV4(w00, w01, w02); PINV4(w03, w04, w05); PINV4(w06, w07, w10);
  PINV4(w11, w12, w13); PINV4(w14, w15, w16); PINV4(w17, w20, w21);
  PINV4(w22, w23, w24); PINV4(w25, w26, w27);

  float b0 = 0.f, b1 = 0.f, b2 = 0.f;
  if (lane == 0) {
    b0 = b_hh[u]; b1 = b_hh[H_DIM + u]; b2 = b_hh[2 * H_DIM + u];
  }

  for (int tt = 0; tt < nsteps; ++tt) {
    const int t = t0 + tt;
    const unsigned long long* hin = htag + (size_t)(t & 1) * H_DIM;
    unsigned long long* hout = htag + (size_t)((t + 1) & 1) * H_DIM;
    float* hl = (t & 1) ? hbuf1 : hbuf0;   // double-buffered stage

    // gx for owner lane (independent; latency hides under poll)
    float gx0 = 0.f, gx1 = 0.f, gx2 = 0.f;
    if (lane == 0) {
      const float* g = gxc + (size_t)tt * G_DIM + u;
      gx0 = g[0]; gx1 = g[H_DIM]; gx2 = g[2 * H_DIM];
    }

    // ---- poll-the-data: 4 u64/thread, coalesced; tag+h in one word ----
    unsigned long long v[4];
    const unsigned tgt = (unsigned)t;
    for (;;) {
      bool ok = true;
#pragma unroll
      for (int j = 0; j < 4; ++j) {
        v[j] = __hip_atomic_load(hin + tid + 512 * j,
                                 __ATOMIC_RELAXED, __HIP_MEMORY_SCOPE_AGENT);
        ok = ok && ((unsigned)v[j] >= tgt);
      }
      if (ok) break;
      __builtin_amdgcn_s_sleep(1);
    }
#pragma unroll
    for (int j = 0; j < 4; ++j)
      hl[tid + 512 * j] = __uint_as_float((unsigned)(v[j] >> 32));
    __syncthreads();   // hl ready (single barrier per step; safety via dbuf)

    // ---- 3 dot products off pinned register weights ----
    float a0 = 0.f, a1 = 0.f, a2 = 0.f;
    const float4* h4 = (const float4*)hl;
    DOT4(w00, w10, w20, lane +   0);
    DOT4(w01, w11, w21, lane +  64);
    DOT4(w02, w12, w22, lane + 128);
    DOT4(w03, w13, w23, lane + 192);
    DOT4(w04, w14, w24, lane + 256);
    DOT4(w05, w15, w25, lane + 320);
    DOT4(w06, w16, w26, lane + 384);
    DOT4(w07, w17, w27, lane + 448);
#pragma unroll
    for (int d = 32; d > 0; d >>= 1) {
      a0 += __shfl_xor(a0, d, 64);
      a1 += __shfl_xor(a1, d, 64);
      a2 += __shfl_xor(a2, d, 64);
    }

    // ---- gates + publish on owner lane ----
    if (lane == 0) {
      const float rr = 1.f / (1.f + expf(-(gx0 + a0 + b0)));
      const float zz = 1.f / (1.f + expf(-(gx1 + a1 + b1)));
      const float nn = tanhf(gx2 + rr * (a2 + b2));
      const float hnew = (1.f - zz) * nn + zz * hl[u];
      const unsigned long long pk =
          ((unsigned long long)__float_as_uint(hnew) << 32) |
          (unsigned long long)(unsigned)(t + 1);
      __hip_atomic_store(hout + u, pk,
                         __ATOMIC_RELAXED, __HIP_MEMORY_SCOPE_AGENT);
      hsbf16[(size_t)t * H_DIM + u] =
          (unsigned short)__bfloat16_as_ushort(__float2bfloat16(hnew));
    }
  }
}

// ---------------- Phase 3a: attention scores (bf16 h_mid, h_last from htag) ---
__global__ __launch_bounds__(256) void attn_scores(
    const unsigned short* __restrict__ hs_bf,
    const unsigned long long* __restrict__ hq,  // slot0 of htag: {h,tag=8192}
    float* __restrict__ s, int n) {
  __shared__ float hl[H_DIM];
  const int tid = threadIdx.x;
  for (int i = tid; i < H_DIM; i += 256)
    hl[i] = __uint_as_float((unsigned)(hq[i] >> 32));
  __syncthreads();
  const int wave = tid >> 6, lane = tid & 63;
  const int t = blockIdx.x * 4 + wave;
  if (t >= n) return;
  const uint4* r4 = (const uint4*)(hs_bf + (size_t)t * H_DIM);
  float sum = 0.f;
#pragma unroll
  for (int u = 0; u < 4; ++u) {
    const int idx = lane + 64 * u;
    uint4 v = r4[idx];
    const float* l = hl + idx * 8;
    sum += bf2f((unsigned short)(v.x & 0xffff)) * l[0];
    sum += bf2f((unsigned short)(v.x >> 16))    * l[1];
    sum += bf2f((unsigned short)(v.y & 0xffff)) * l[2];
    sum += bf2f((unsigned short)(v.y >> 16))    * l[3];
    sum += bf2f((unsigned short)(v.z & 0xffff)) * l[4];
    sum += bf2f((unsigned short)(v.z >> 16))    * l[5];
    sum += bf2f((unsigned short)(v.w & 0xffff)) * l[6];
    sum += bf2f((unsigned short)(v.w >> 16))    * l[7];
  }
#pragma unroll
  for (int d = 32; d > 0; d >>= 1) sum += __shfl_xor(sum, d, 64);
  if (lane == 0) s[t] = sum;
}

// ---------------- Phase 3b: softmax stats ----------------
__global__ __launch_bounds__(1024) void softmax_stats(
    const float* __restrict__ s, int n, float* __restrict__ red) {
  __shared__ float buf[1024];
  const int tid = threadIdx.x;
  float m = -3.4e38f;
  for (int i = tid; i < n; i += 1024) m = fmaxf(m, s[i]);
  buf[tid] = m;
  __syncthreads();
  for (int d = 512; d > 0; d >>= 1) {
    if (tid < d) buf[tid] = fmaxf(buf[tid], buf[tid + d]);
    __syncthreads();
  }
  const float mm = buf[0];
  __syncthreads();
  float sum = 0.f;
  for (int i = tid; i < n; i += 1024) sum += expf(s[i] - mm);
  buf[tid] = sum;
  __syncthreads();
  for (int d = 512; d > 0; d >>= 1) {
    if (tid < d) buf[tid] += buf[tid + d];
    __syncthreads();
  }
  if (tid == 0) { red[0] = mm; red[1] = buf[0]; }
}

// ---------------- Phase 3c: weighted sum partials (bf16 h_mid) ----------------
__global__ __launch_bounds__(256) void attn_wsum(
    const unsigned short* __restrict__ hs_bf, const float* __restrict__ s,
    const float* __restrict__ red, float* __restrict__ c_part, int n) {
  const int tid = threadIdx.x;
  const float m = red[0];
  const float inv = 1.f / red[1];
  const int tchunk = (n + 63) / 64;
  const int t0 = blockIdx.x * tchunk;
  const int t1 = min(t0 + tchunk, n);
  float acc[8] = {};
  for (int t = t0; t < t1; ++t) {
    const float w = expf(s[t] - m) * inv;
    const uint4 v = ((const uint4*)(hs_bf + (size_t)t * H_DIM))[tid];
    acc[0] += w * bf2f((unsigned short)(v.x & 0xffff));
    acc[1] += w * bf2f((unsigned short)(v.x >> 16));
    acc[2] += w * bf2f((unsigned short)(v.y & 0xffff));
    acc[3] += w * bf2f((unsigned short)(v.y >> 16));
    acc[4] += w * bf2f((unsigned short)(v.z & 0xffff));
    acc[5] += w * bf2f((unsigned short)(v.z >> 16));
    acc[6] += w * bf2f((unsigned short)(v.w & 0xffff));
    acc[7] += w * bf2f((unsigned short)(v.w >> 16));
  }
  float* dst = c_part + (size_t)blockIdx.x * H_DIM + tid * 8;
#pragma unroll
  for (int k = 0; k < 8; ++k) dst[k] = acc[k];
}

// ---------------- Phase 3d: reduce partials ----------------
__global__ __launch_bounds__(256) void reduce_c(
    const float* __restrict__ c_part, float* __restrict__ c) {
  const int i = blockIdx.x * 256 + threadIdx.x;
  float sum = 0.f;
  for (int b = 0; b < 64; ++b) sum += c_part[(size_t)b * H_DIM + i];
  c[i] = sum;
}

// ---------------- Phase 3e: output heads ----------------
__global__ __launch_bounds__(64) void logits_kernel(
    const float* __restrict__ W_o, const float* __restrict__ b_o,
    const float* __restrict__ W_d, const float* __restrict__ b_d,
    const float* __restrict__ c, float* __restrict__ out) {
  const int j = blockIdx.x;
  const int lane = threadIdx.x;
  const float* W; const float* bb; int jj;
  if (j < A_DIM) { W = W_o; bb = b_o; jj = j; }
  else { W = W_d; bb = b_d; jj = j - A_DIM; }
  const float4* w4 = (const float4*)(W + (size_t)jj * H_DIM);
  const float4* c4 = (const float4*)c;
  float sum = 0.f;
#pragma unroll
  for (int u = 0; u < 8; ++u) {
    float4 a = w4[lane + 64 * u];
    float4 b = c4[lane + 64 * u];
    sum += a.x * b.x + a.y * b.y + a.z * b.z + a.w * b.w;
  }
#pragma unroll
  for (int d = 32; d > 0; d >>= 1) sum += __shfl_xor(sum, d, 64);
  if (lane == 0) out[j] = sum + bb[jj];
}

extern "C" void kernel_launch(void* const* d_in, const int* in_sizes, int n_in,
                              void* d_out, int out_size, void* d_ws, size_t ws_size,
                              hipStream_t stream) {
  const float* obs  = (const float*)d_in[0];
  const float* W_ih = (const float*)d_in[1];
  const float* W_hh = (const float*)d_in[2];
  const float* b_ih = (const float*)d_in[3];
  const float* b_hh = (const float*)d_in[4];
  const float* W_o  = (const float*)d_in[5];
  const float* b_o  = (const float*)d_in[6];
  const float* W_d  = (const float*)d_in[7];
  const float* b_d  = (const float*)d_in[8];
  float* out = (float*)d_out;
  float* ws = (float*)d_ws;

  float* gxc      = ws + OFF_GXC;
  unsigned long long* htag = (unsigned long long*)(ws + OFF_HTAG);
  float* s        = ws + OFF_S;
  float* red      = ws + OFF_RED;
  float* c_part   = ws + OFF_CPART;
  float* c        = ws + OFF_C;
  unsigned short* hsbf16 = (unsigned short*)(ws + OFF_HSBF);

  // slot0 = {h=0, tag=0} for all units -> valid input for step t=0
  hipMemsetAsync(htag, 0, 2 * H_DIM * sizeof(unsigned long long), stream);

  for (int ci = 0; ci < T_DIM / CHUNK; ++ci) {
    gemm_gx<<<dim3(CHUNK / BM, G_DIM / BN), 256, 0, stream>>>(
        obs + (size_t)ci * CHUNK * O_DIM, W_ih, b_ih, gxc);
    scan_chunk<<<NBLK, 512, 0, stream>>>(
        W_hh, b_hh, gxc, htag, hsbf16, ci * CHUNK, CHUNK);
  }
  // final h (tag 8192, even) is in htag slot 0
  const unsigned long long* h_last = htag;

  const int n = T_DIM - 1;  // 8191 mid states
  attn_scores<<<(n + 3) / 4, 256, 0, stream>>>(hsbf16, h_last, s, n);
  softmax_stats<<<1, 1024, 0, stream>>>(s, n, red);
  attn_wsum<<<64, 256, 0, stream>>>(hsbf16, s, red, c_part, n);
  reduce_c<<<H_DIM / 256, 256, 0, stream>>>(c_part, c);
  logits_kernel<<<2 * A_DIM, 64, 0, stream>>>(W_o, b_o, W_d, b_d, c, out);
}

// Round 10
// 45978.174 us; speedup vs baseline: 1.1967x; 1.1967x over previous
//
#include <hip/hip_runtime.h>
#include <hip/hip_bf16.h>

#define T_DIM 8192
#define O_DIM 1024
#define H_DIM 2048
#define G_DIM 6144   // 3*H
#define A_DIM 512
#define CHUNK 512    // steps per scan launch
#define NBLK 256     // scan blocks (1 per CU; forced by dummy LDS)
#define PROBE_STEPS 2048

// ---- workspace layout (float offsets; total ~46.8 MB) ----
#define OFF_GXC    0ull          // CHUNK x 3H fp32            (3,145,728 f)
#define OFF_HTAG   3145728ull    // 2 x H u64 {h,tag}          (8,192 f)
#define OFF_S      3153920ull    // 8192 scores fp32
#define OFF_RED    3162112ull    // max, sum (+pad)            (16 f)
#define OFF_CPART  3162128ull    // 64 x 2048 fp32             (131,072 f)
#define OFF_C      3293200ull    // 2048 fp32
#define OFF_HSBF   3295248ull    // T x H bf16                 (8,388,608 f)
#define OFF_PROBEA 11683856ull   // 2 x 2048 u64               (8,192 f)
#define OFF_PROBEC 11692048ull   // 2 x 1024 u64               (4,096 f)

__device__ __forceinline__ float bf2f(unsigned short u) {
  return __uint_as_float(((unsigned)u) << 16);
}

// ---------------- Phase 1: gx chunk = obs_chunk @ W_ih^T + b_ih ----------------
#define BM 64
#define BN 64
#define BK 16
__global__ __launch_bounds__(256) void gemm_gx(
    const float* __restrict__ A,   // CHUNK x O
    const float* __restrict__ B,   // 3H x O
    const float* __restrict__ bias,
    float* __restrict__ C) {       // CHUNK x 3H
  __shared__ float As[BM][BK + 1];
  __shared__ float Bs[BN][BK + 1];
  const int bm = blockIdx.x * BM;
  const int bn = blockIdx.y * BN;
  const int tid = threadIdx.x;
  const int tr = tid / 16, tc = tid % 16;
  float acc[4][4] = {};
  for (int k0 = 0; k0 < O_DIM; k0 += BK) {
    for (int i = tid; i < BM * BK; i += 256) {
      int r = i / BK, c = i % BK;
      As[r][c] = A[(size_t)(bm + r) * O_DIM + k0 + c];
    }
    for (int i = tid; i < BN * BK; i += 256) {
      int r = i / BK, c = i % BK;
      Bs[r][c] = B[(size_t)(bn + r) * O_DIM + k0 + c];
    }
    __syncthreads();
#pragma unroll
    for (int kk = 0; kk < BK; ++kk) {
      float a[4], b[4];
#pragma unroll
      for (int i = 0; i < 4; ++i) a[i] = As[tr * 4 + i][kk];
#pragma unroll
      for (int j = 0; j < 4; ++j) b[j] = Bs[tc * 4 + j][kk];
#pragma unroll
      for (int i = 0; i < 4; ++i)
#pragma unroll
        for (int j = 0; j < 4; ++j) acc[i][j] += a[i] * b[j];
    }
    __syncthreads();
  }
#pragma unroll
  for (int i = 0; i < 4; ++i)
#pragma unroll
    for (int j = 0; j < 4; ++j) {
      int r = bm + tr * 4 + i, cc = bn + tc * 4 + j;
      C[(size_t)r * G_DIM + cc] = acc[i][j] + bias[cc];
    }
}

// ---------------- Phase 2: persistent GRU scan (ROUND-7 CHAMPION, verbatim) ---
// 256 blocks x 512 threads (8 waves). Wave wv owns unit u = blk*8+wv. Weights
// nominally in VGPRs (compiler re-streams them: VGPR=88, FETCH 94MB — known,
// accepted; this exact body measured 2.03ms/chunk). Poll-the-data u64 {h,tag}
// at relaxed agent scope. Dummy LDS forces 1 block/CU.
__global__ __launch_bounds__(512, 2) void scan_chunk(
    const float* __restrict__ W_hh,        // 3H x H fp32
    const float* __restrict__ b_hh,        // 3H
    const float* __restrict__ gxc,         // CHUNK x 3H
    unsigned long long* __restrict__ htag, // 2 x H {h,tag}
    unsigned short* __restrict__ hsbf16,   // T x H bf16
    int t0, int nsteps) {
  __shared__ char smem[98304];             // forces 1 block/CU
  float* hlds = (float*)smem;              // H_DIM floats (8 KB used)
  const int tid = threadIdx.x;
  const int lane = tid & 63;
  const int wv = tid >> 6;                 // wave 0..7
  const int blk = blockIdx.x;
  const int u = blk * 8 + wv;              // owned unit

  // ---- weights to VGPRs (once per launch), fp32 ----
  float4 warr[3][8];
#pragma unroll
  for (int g = 0; g < 3; ++g) {
    const float4* wrow = (const float4*)(W_hh + (size_t)(g * H_DIM + u) * H_DIM);
#pragma unroll
    for (int j = 0; j < 8; ++j) warr[g][j] = wrow[lane + 64 * j];
  }
  float b0 = 0.f, b1 = 0.f, b2 = 0.f;
  if (lane == 0) {
    b0 = b_hh[u]; b1 = b_hh[H_DIM + u]; b2 = b_hh[2 * H_DIM + u];
  }

  for (int tt = 0; tt < nsteps; ++tt) {
    const int t = t0 + tt;
    const unsigned long long* hin = htag + (size_t)(t & 1) * H_DIM;
    unsigned long long* hout = htag + (size_t)((t + 1) & 1) * H_DIM;

    // gx for owner lane (independent; latency hides under poll)
    float gx0 = 0.f, gx1 = 0.f, gx2 = 0.f;
    if (lane == 0) {
      const float* g = gxc + (size_t)tt * G_DIM + u;
      gx0 = g[0]; gx1 = g[H_DIM]; gx2 = g[2 * H_DIM];
    }

    __syncthreads();   // previous step's hlds readers are done

    // ---- poll-the-data: 4 u64/thread, coalesced ----
    unsigned long long v[4];
    const unsigned tgt = (unsigned)t;
    for (;;) {
      bool ok = true;
#pragma unroll
      for (int j = 0; j < 4; ++j) {
        v[j] = __hip_atomic_load(hin + tid + 512 * j,
                                 __ATOMIC_RELAXED, __HIP_MEMORY_SCOPE_AGENT);
        ok = ok && ((unsigned)v[j] >= tgt);
      }
      if (ok) break;
      __builtin_amdgcn_s_sleep(1);
    }
#pragma unroll
    for (int j = 0; j < 4; ++j)
      hlds[tid + 512 * j] = __uint_as_float((unsigned)(v[j] >> 32));
    __syncthreads();   // hlds ready

    // ---- 3 dot products ----
    float a0 = 0.f, a1 = 0.f, a2 = 0.f;
    const float4* h4 = (const float4*)hlds;
#pragma unroll
    for (int j = 0; j < 8; ++j) {
      const float4 h = h4[lane + 64 * j];
      a0 += warr[0][j].x * h.x + warr[0][j].y * h.y
          + warr[0][j].z * h.z + warr[0][j].w * h.w;
      a1 += warr[1][j].x * h.x + warr[1][j].y * h.y
          + warr[1][j].z * h.z + warr[1][j].w * h.w;
      a2 += warr[2][j].x * h.x + warr[2][j].y * h.y
          + warr[2][j].z * h.z + warr[2][j].w * h.w;
    }
#pragma unroll
    for (int d = 32; d > 0; d >>= 1) {
      a0 += __shfl_xor(a0, d, 64);
      a1 += __shfl_xor(a1, d, 64);
      a2 += __shfl_xor(a2, d, 64);
    }

    // ---- gates + publish on owner lane ----
    if (lane == 0) {
      const float rr = 1.f / (1.f + expf(-(gx0 + a0 + b0)));
      const float zz = 1.f / (1.f + expf(-(gx1 + a1 + b1)));
      const float nn = tanhf(gx2 + rr * (a2 + b2));
      const float hnew = (1.f - zz) * nn + zz * hlds[u];
      const unsigned long long pk =
          ((unsigned long long)__float_as_uint(hnew) << 32) |
          (unsigned long long)(unsigned)(t + 1);
      __hip_atomic_store(hout + u, pk,
                         __ATOMIC_RELAXED, __HIP_MEMORY_SCOPE_AGENT);
      hsbf16[(size_t)t * H_DIM + u] =
          (unsigned short)__bfloat16_as_ushort(__float2bfloat16(hnew));
    }
  }
}

// ---------------- ABLATION PROBE: pure sync, zero compute --------------------
// Identical poll/publish/LDS-footprint pattern to scan_chunk but no FMA/gates.
// per-step sync floor = dur_us / PROBE_STEPS. Launched on scratch buffers after
// the real pipeline; deterministic (tags only).
__global__ __launch_bounds__(512, 2) void sync_probe(
    unsigned long long* __restrict__ ptag,  // 2 x (8*gridDim) {0,tag}
    int nsteps, int nwords) {               // nwords = (8*gridDim)/512
  __shared__ char smem[98304];              // same 1-block/CU exclusivity
  const int tid = threadIdx.x;
  const int lane = tid & 63;
  const int wv = tid >> 6;
  const int u = blockIdx.x * 8 + wv;
  const int NU = gridDim.x * 8;
  ((volatile char*)smem)[tid] = 0;          // keep LDS allocated

  for (int tt = 0; tt < nsteps; ++tt) {
    const unsigned long long* pin = ptag + (size_t)(tt & 1) * NU;
    unsigned long long* pout = ptag + (size_t)((tt + 1) & 1) * NU;
    __syncthreads();
    const unsigned tgt = (unsigned)tt;
    for (;;) {
      bool ok = true;
      for (int j = 0; j < nwords; ++j) {
        const unsigned long long v = __hip_atomic_load(
            pin + tid + 512 * j, __ATOMIC_RELAXED, __HIP_MEMORY_SCOPE_AGENT);
        ok = ok && ((unsigned)v >= tgt);
      }
      if (ok) break;
      __builtin_amdgcn_s_sleep(1);
    }
    __syncthreads();
    if (lane == 0)
      __hip_atomic_store(pout + u, (unsigned long long)(unsigned)(tt + 1),
                         __ATOMIC_RELAXED, __HIP_MEMORY_SCOPE_AGENT);
  }
}

// ---------------- Phase 3a: attention scores (bf16 h_mid, h_last from htag) ---
__global__ __launch_bounds__(256) void attn_scores(
    const unsigned short* __restrict__ hs_bf,
    const unsigned long long* __restrict__ hq,  // slot0 of htag: {h,tag=8192}
    float* __restrict__ s, int n) {
  __shared__ float hl[H_DIM];
  const int tid = threadIdx.x;
  for (int i = tid; i < H_DIM; i += 256)
    hl[i] = __uint_as_float((unsigned)(hq[i] >> 32));
  __syncthreads();
  const int wave = tid >> 6, lane = tid & 63;
  const int t = blockIdx.x * 4 + wave;
  if (t >= n) return;
  const uint4* r4 = (const uint4*)(hs_bf + (size_t)t * H_DIM);
  float sum = 0.f;
#pragma unroll
  for (int u = 0; u < 4; ++u) {
    const int idx = lane + 64 * u;
    uint4 v = r4[idx];
    const float* l = hl + idx * 8;
    sum += bf2f((unsigned short)(v.x & 0xffff)) * l[0];
    sum += bf2f((unsigned short)(v.x >> 16))    * l[1];
    sum += bf2f((unsigned short)(v.y & 0xffff)) * l[2];
    sum += bf2f((unsigned short)(v.y >> 16))    * l[3];
    sum += bf2f((unsigned short)(v.z & 0xffff)) * l[4];
    sum += bf2f((unsigned short)(v.z >> 16))    * l[5];
    sum += bf2f((unsigned short)(v.w & 0xffff)) * l[6];
    sum += bf2f((unsigned short)(v.w >> 16))    * l[7];
  }
#pragma unroll
  for (int d = 32; d > 0; d >>= 1) sum += __shfl_xor(sum, d, 64);
  if (lane == 0) s[t] = sum;
}

// ---------------- Phase 3b: softmax stats ----------------
__global__ __launch_bounds__(1024) void softmax_stats(
    const float* __restrict__ s, int n, float* __restrict__ red) {
  __shared__ float buf[1024];
  const int tid = threadIdx.x;
  float m = -3.4e38f;
  for (int i = tid; i < n; i += 1024) m = fmaxf(m, s[i]);
  buf[tid] = m;
  __syncthreads();
  for (int d = 512; d > 0; d >>= 1) {
    if (tid < d) buf[tid] = fmaxf(buf[tid], buf[tid + d]);
    __syncthreads();
  }
  const float mm = buf[0];
  __syncthreads();
  float sum = 0.f;
  for (int i = tid; i < n; i += 1024) sum += expf(s[i] - mm);
  buf[tid] = sum;
  __syncthreads();
  for (int d = 512; d > 0; d >>= 1) {
    if (tid < d) buf[tid] += buf[tid + d];
    __syncthreads();
  }
  if (tid == 0) { red[0] = mm; red[1] = buf[0]; }
}

// ---------------- Phase 3c: weighted sum partials (bf16 h_mid) ----------------
__global__ __launch_bounds__(256) void attn_wsum(
    const unsigned short* __restrict__ hs_bf, const float* __restrict__ s,
    const float* __restrict__ red, float* __restrict__ c_part, int n) {
  const int tid = threadIdx.x;
  const float m = red[0];
  const float inv = 1.f / red[1];
  const int tchunk = (n + 63) / 64;
  const int t0 = blockIdx.x * tchunk;
  const int t1 = min(t0 + tchunk, n);
  float acc[8] = {};
  for (int t = t0; t < t1; ++t) {
    const float w = expf(s[t] - m) * inv;
    const uint4 v = ((const uint4*)(hs_bf + (size_t)t * H_DIM))[tid];
    acc[0] += w * bf2f((unsigned short)(v.x & 0xffff));
    acc[1] += w * bf2f((unsigned short)(v.x >> 16));
    acc[2] += w * bf2f((unsigned short)(v.y & 0xffff));
    acc[3] += w * bf2f((unsigned short)(v.y >> 16));
    acc[4] += w * bf2f((unsigned short)(v.z & 0xffff));
    acc[5] += w * bf2f((unsigned short)(v.z >> 16));
    acc[6] += w * bf2f((unsigned short)(v.w & 0xffff));
    acc[7] += w * bf2f((unsigned short)(v.w >> 16));
  }
  float* dst = c_part + (size_t)blockIdx.x * H_DIM + tid * 8;
#pragma unroll
  for (int k = 0; k < 8; ++k) dst[k] = acc[k];
}

// ---------------- Phase 3d: reduce partials ----------------
__global__ __launch_bounds__(256) void reduce_c(
    const float* __restrict__ c_part, float* __restrict__ c) {
  const int i = blockIdx.x * 256 + threadIdx.x;
  float sum = 0.f;
  for (int b = 0; b < 64; ++b) sum += c_part[(size_t)b * H_DIM + i];
  c[i] = sum;
}

// ---------------- Phase 3e: output heads ----------------
__global__ __launch_bounds__(64) void logits_kernel(
    const float* __restrict__ W_o, const float* __restrict__ b_o,
    const float* __restrict__ W_d, const float* __restrict__ b_d,
    const float* __restrict__ c, float* __restrict__ out) {
  const int j = blockIdx.x;
  const int lane = threadIdx.x;
  const float* W; const float* bb; int jj;
  if (j < A_DIM) { W = W_o; bb = b_o; jj = j; }
  else { W = W_d; bb = b_d; jj = j - A_DIM; }
  const float4* w4 = (const float4*)(W + (size_t)jj * H_DIM);
  const float4* c4 = (const float4*)c;
  float sum = 0.f;
#pragma unroll
  for (int u = 0; u < 8; ++u) {
    float4 a = w4[lane + 64 * u];
    float4 b = c4[lane + 64 * u];
    sum += a.x * b.x + a.y * b.y + a.z * b.z + a.w * b.w;
  }
#pragma unroll
  for (int d = 32; d > 0; d >>= 1) sum += __shfl_xor(sum, d, 64);
  if (lane == 0) out[j] = sum + bb[jj];
}

extern "C" void kernel_launch(void* const* d_in, const int* in_sizes, int n_in,
                              void* d_out, int out_size, void* d_ws, size_t ws_size,
                              hipStream_t stream) {
  const float* obs  = (const float*)d_in[0];
  const float* W_ih = (const float*)d_in[1];
  const float* W_hh = (const float*)d_in[2];
  const float* b_ih = (const float*)d_in[3];
  const float* b_hh = (const float*)d_in[4];
  const float* W_o  = (const float*)d_in[5];
  const float* b_o  = (const float*)d_in[6];
  const float* W_d  = (const float*)d_in[7];
  const float* b_d  = (const float*)d_in[8];
  float* out = (float*)d_out;
  float* ws = (float*)d_ws;

  float* gxc      = ws + OFF_GXC;
  unsigned long long* htag = (unsigned long long*)(ws + OFF_HTAG);
  float* s        = ws + OFF_S;
  float* red      = ws + OFF_RED;
  float* c_part   = ws + OFF_CPART;
  float* c        = ws + OFF_C;
  unsigned short* hsbf16 = (unsigned short*)(ws + OFF_HSBF);
  unsigned long long* probeA = (unsigned long long*)(ws + OFF_PROBEA);
  unsigned long long* probeC = (unsigned long long*)(ws + OFF_PROBEC);

  // slot0 = {h=0, tag=0} for all units -> valid input for step t=0
  hipMemsetAsync(htag, 0, 2 * H_DIM * sizeof(unsigned long long), stream);
  hipMemsetAsync(probeA, 0, 2 * 2048 * sizeof(unsigned long long), stream);
  hipMemsetAsync(probeC, 0, 2 * 1024 * sizeof(unsigned long long), stream);

  for (int ci = 0; ci < T_DIM / CHUNK; ++ci) {
    gemm_gx<<<dim3(CHUNK / BM, G_DIM / BN), 256, 0, stream>>>(
        obs + (size_t)ci * CHUNK * O_DIM, W_ih, b_ih, gxc);
    scan_chunk<<<NBLK, 512, 0, stream>>>(
        W_hh, b_hh, gxc, htag, hsbf16, ci * CHUNK, CHUNK);
  }
  // final h (tag 8192, even) is in htag slot 0
  const unsigned long long* h_last = htag;

  const int n = T_DIM - 1;  // 8191 mid states
  attn_scores<<<(n + 3) / 4, 256, 0, stream>>>(hsbf16, h_last, s, n);
  softmax_stats<<<1, 1024, 0, stream>>>(s, n, red);
  attn_wsum<<<64, 256, 0, stream>>>(hsbf16, s, red, c_part, n);
  reduce_c<<<H_DIM / 256, 256, 0, stream>>>(c_part, c);
  logits_kernel<<<2 * A_DIM, 64, 0, stream>>>(W_o, b_o, W_d, b_d, c, out);

  // ---- ablation probes (pure sync floor; do not touch d_out) ----
  sync_probe<<<256, 512, 0, stream>>>(probeA, PROBE_STEPS, 4);
  sync_probe<<<128, 512, 0, stream>>>(probeC, PROBE_STEPS, 2);
}

// Round 11
// 23126.903 us; speedup vs baseline: 2.3792x; 1.9881x over previous
//
#include <hip/hip_runtime.h>
#include <hip/hip_bf16.h>

#define T_DIM 8192
#define O_DIM 1024
#define H_DIM 2048
#define G_DIM 6144   // 3*H
#define A_DIM 512
#define CHUNK 512    // steps per scan launch
#define NBLK 256     // scan blocks (1 per CU; forced by dummy LDS)

// ---- workspace layout (float offsets; total ~46.7 MB, proven safe) ----
#define OFF_GXC   0ull          // CHUNK x 3H fp32            (3,145,728 f)
#define OFF_HTAG  3145728ull    // 2 x H u64 {h,tag}          (8,192 f)
#define OFF_S     3153920ull    // 8192 scores fp32
#define OFF_RED   3162112ull    // max, sum (+pad)            (16 f)
#define OFF_CPART 3162128ull    // 64 x 2048 fp32             (131,072 f)
#define OFF_C     3293200ull    // 2048 fp32
#define OFF_HSBF  3295248ull    // T x H bf16                 (8,388,608 f)

__device__ __forceinline__ float bf2f(unsigned short u) {
  return __uint_as_float(((unsigned)u) << 16);
}

// ---------------- Phase 1: gx chunk = obs_chunk @ W_ih^T + b_ih ----------------
#define BM 64
#define BN 64
#define BK 16
__global__ __launch_bounds__(256) void gemm_gx(
    const float* __restrict__ A,   // CHUNK x O
    const float* __restrict__ B,   // 3H x O
    const float* __restrict__ bias,
    float* __restrict__ C) {       // CHUNK x 3H
  __shared__ float As[BM][BK + 1];
  __shared__ float Bs[BN][BK + 1];
  const int bm = blockIdx.x * BM;
  const int bn = blockIdx.y * BN;
  const int tid = threadIdx.x;
  const int tr = tid / 16, tc = tid % 16;
  float acc[4][4] = {};
  for (int k0 = 0; k0 < O_DIM; k0 += BK) {
    for (int i = tid; i < BM * BK; i += 256) {
      int r = i / BK, c = i % BK;
      As[r][c] = A[(size_t)(bm + r) * O_DIM + k0 + c];
    }
    for (int i = tid; i < BN * BK; i += 256) {
      int r = i / BK, c = i % BK;
      Bs[r][c] = B[(size_t)(bn + r) * O_DIM + k0 + c];
    }
    __syncthreads();
#pragma unroll
    for (int kk = 0; kk < BK; ++kk) {
      float a[4], b[4];
#pragma unroll
      for (int i = 0; i < 4; ++i) a[i] = As[tr * 4 + i][kk];
#pragma unroll
      for (int j = 0; j < 4; ++j) b[j] = Bs[tc * 4 + j][kk];
#pragma unroll
      for (int i = 0; i < 4; ++i)
#pragma unroll
        for (int j = 0; j < 4; ++j) acc[i][j] += a[i] * b[j];
    }
    __syncthreads();
  }
#pragma unroll
  for (int i = 0; i < 4; ++i)
#pragma unroll
    for (int j = 0; j < 4; ++j) {
      int r = bm + tr * 4 + i, cc = bn + tc * 4 + j;
      C[(size_t)r * G_DIM + cc] = acc[i][j] + bias[cc];
    }
}

// ---------------- Phase 2: persistent GRU scan -------------------------------
// r7 champion body with ONE mechanism change: the publish.
//   OLD: 8 waves each issue one 8B agent-atomic store -> 8 serialized
//        partial-line updates at the IF per block per step.
//   NEW: owner lanes ds_write {h,tag} to an 8-slot LDS stage; after a barrier,
//        wave 0 lanes 0-7 store the whole 64B line in ONE coalesced
//        instruction -> one IF transaction per block.
// hlds double-buffered -> loop-top barrier removed; all global stores issued
// after the last barrier so their acks drain under the next step's poll.
__global__ __launch_bounds__(512, 2) void scan_chunk(
    const float* __restrict__ W_hh,        // 3H x H fp32
    const float* __restrict__ b_hh,        // 3H
    const float* __restrict__ gxc,         // CHUNK x 3H
    unsigned long long* __restrict__ htag, // 2 x H {h,tag}
    unsigned short* __restrict__ hsbf16,   // T x H bf16
    int t0, int nsteps) {
  __shared__ char smem[98304];             // forces 1 block/CU
  float* hlbuf0 = (float*)smem;                          // H_DIM floats
  float* hlbuf1 = (float*)(smem + 8192);                 // H_DIM floats
  unsigned long long* stage = (unsigned long long*)(smem + 16384);  // 8 u64
  const int tid = threadIdx.x;
  const int lane = tid & 63;
  const int wv = tid >> 6;                 // wave 0..7
  const int blk = blockIdx.x;
  const int u = blk * 8 + wv;              // owned unit

  // ---- weights to VGPRs (once per launch), fp32 (compiler re-streams; known) --
  float4 warr[3][8];
#pragma unroll
  for (int g = 0; g < 3; ++g) {
    const float4* wrow = (const float4*)(W_hh + (size_t)(g * H_DIM + u) * H_DIM);
#pragma unroll
    for (int j = 0; j < 8; ++j) warr[g][j] = wrow[lane + 64 * j];
  }
  float b0 = 0.f, b1 = 0.f, b2 = 0.f;
  if (lane == 0) {
    b0 = b_hh[u]; b1 = b_hh[H_DIM + u]; b2 = b_hh[2 * H_DIM + u];
  }

  for (int tt = 0; tt < nsteps; ++tt) {
    const int t = t0 + tt;
    const unsigned long long* hin = htag + (size_t)(t & 1) * H_DIM;
    unsigned long long* hout = htag + (size_t)((t + 1) & 1) * H_DIM;
    float* hl = (t & 1) ? hlbuf1 : hlbuf0;   // double-buffered stage

    // gx for owner lane (issued early; drains at the barrier after poll)
    float gx0 = 0.f, gx1 = 0.f, gx2 = 0.f;
    if (lane == 0) {
      const float* g = gxc + (size_t)tt * G_DIM + u;
      gx0 = g[0]; gx1 = g[H_DIM]; gx2 = g[2 * H_DIM];
    }

    // ---- (A) poll-the-data: 4 u64/thread, coalesced ----
    unsigned long long v[4];
    const unsigned tgt = (unsigned)t;
    for (;;) {
      bool ok = true;
#pragma unroll
      for (int j = 0; j < 4; ++j) {
        v[j] = __hip_atomic_load(hin + tid + 512 * j,
                                 __ATOMIC_RELAXED, __HIP_MEMORY_SCOPE_AGENT);
        ok = ok && ((unsigned)v[j] >= tgt);
      }
      if (ok) break;
      __builtin_amdgcn_s_sleep(1);
    }
#pragma unroll
    for (int j = 0; j < 4; ++j)
      hl[tid + 512 * j] = __uint_as_float((unsigned)(v[j] >> 32));
    __syncthreads();   // (B) hl ready

    // ---- (C) 3 dot products ----
    float a0 = 0.f, a1 = 0.f, a2 = 0.f;
    const float4* h4 = (const float4*)hl;
#pragma unroll
    for (int j = 0; j < 8; ++j) {
      const float4 h = h4[lane + 64 * j];
      a0 += warr[0][j].x * h.x + warr[0][j].y * h.y
          + warr[0][j].z * h.z + warr[0][j].w * h.w;
      a1 += warr[1][j].x * h.x + warr[1][j].y * h.y
          + warr[1][j].z * h.z + warr[1][j].w * h.w;
      a2 += warr[2][j].x * h.x + warr[2][j].y * h.y
          + warr[2][j].z * h.z + warr[2][j].w * h.w;
    }
#pragma unroll
    for (int d = 32; d > 0; d >>= 1) {
      a0 += __shfl_xor(a0, d, 64);
      a1 += __shfl_xor(a1, d, 64);
      a2 += __shfl_xor(a2, d, 64);
    }

    // ---- (D) gates on owner lane; stage {h,tag} in LDS ----
    float hnew = 0.f;
    if (lane == 0) {
      const float rr = 1.f / (1.f + expf(-(gx0 + a0 + b0)));
      const float zz = 1.f / (1.f + expf(-(gx1 + a1 + b1)));
      const float nn = tanhf(gx2 + rr * (a2 + b2));
      hnew = (1.f - zz) * nn + zz * hl[u];
      stage[wv] = ((unsigned long long)__float_as_uint(hnew) << 32) |
                  (unsigned long long)(unsigned)(t + 1);
    }
    __syncthreads();   // (E) stage ready

    // ---- (F) single-wave coalesced publish: one 64B line, one instruction ----
    if (tid < 8) {
      __hip_atomic_store(hout + blk * 8 + tid, stage[tid],
                         __ATOMIC_RELAXED, __HIP_MEMORY_SCOPE_AGENT);
    }
    // ---- (G) attention state (off critical path; drains under next poll) ----
    if (lane == 0) {
      hsbf16[(size_t)t * H_DIM + u] =
          (unsigned short)__bfloat16_as_ushort(__float2bfloat16(hnew));
    }
  }
}

// ---------------- Phase 3a: attention scores (bf16 h_mid, h_last from htag) ---
__global__ __launch_bounds__(256) void attn_scores(
    const unsigned short* __restrict__ hs_bf,
    const unsigned long long* __restrict__ hq,  // slot0 of htag: {h,tag=8192}
    float* __restrict__ s, int n) {
  __shared__ float hl[H_DIM];
  const int tid = threadIdx.x;
  for (int i = tid; i < H_DIM; i += 256)
    hl[i] = __uint_as_float((unsigned)(hq[i] >> 32));
  __syncthreads();
  const int wave = tid >> 6, lane = tid & 63;
  const int t = blockIdx.x * 4 + wave;
  if (t >= n) return;
  const uint4* r4 = (const uint4*)(hs_bf + (size_t)t * H_DIM);
  float sum = 0.f;
#pragma unroll
  for (int u = 0; u < 4; ++u) {
    const int idx = lane + 64 * u;
    uint4 v = r4[idx];
    const float* l = hl + idx * 8;
    sum += bf2f((unsigned short)(v.x & 0xffff)) * l[0];
    sum += bf2f((unsigned short)(v.x >> 16))    * l[1];
    sum += bf2f((unsigned short)(v.y & 0xffff)) * l[2];
    sum += bf2f((unsigned short)(v.y >> 16))    * l[3];
    sum += bf2f((unsigned short)(v.z & 0xffff)) * l[4];
    sum += bf2f((unsigned short)(v.z >> 16))    * l[5];
    sum += bf2f((unsigned short)(v.w & 0xffff)) * l[6];
    sum += bf2f((unsigned short)(v.w >> 16))    * l[7];
  }
#pragma unroll
  for (int d = 32; d > 0; d >>= 1) sum += __shfl_xor(sum, d, 64);
  if (lane == 0) s[t] = sum;
}

// ---------------- Phase 3b: softmax stats ----------------
__global__ __launch_bounds__(1024) void softmax_stats(
    const float* __restrict__ s, int n, float* __restrict__ red) {
  __shared__ float buf[1024];
  const int tid = threadIdx.x;
  float m = -3.4e38f;
  for (int i = tid; i < n; i += 1024) m = fmaxf(m, s[i]);
  buf[tid] = m;
  __syncthreads();
  for (int d = 512; d > 0; d >>= 1) {
    if (tid < d) buf[tid] = fmaxf(buf[tid], buf[tid + d]);
    __syncthreads();
  }
  const float mm = buf[0];
  __syncthreads();
  float sum = 0.f;
  for (int i = tid; i < n; i += 1024) sum += expf(s[i] - mm);
  buf[tid] = sum;
  __syncthreads();
  for (int d = 512; d > 0; d >>= 1) {
    if (tid < d) buf[tid] += buf[tid + d];
    __syncthreads();
  }
  if (tid == 0) { red[0] = mm; red[1] = buf[0]; }
}

// ---------------- Phase 3c: weighted sum partials (bf16 h_mid) ----------------
__global__ __launch_bounds__(256) void attn_wsum(
    const unsigned short* __restrict__ hs_bf, const float* __restrict__ s,
    const float* __restrict__ red, float* __restrict__ c_part, int n) {
  const int tid = threadIdx.x;
  const float m = red[0];
  const float inv = 1.f / red[1];
  const int tchunk = (n + 63) / 64;
  const int t0 = blockIdx.x * tchunk;
  const int t1 = min(t0 + tchunk, n);
  float acc[8] = {};
  for (int t = t0; t < t1; ++t) {
    const float w = expf(s[t] - m) * inv;
    const uint4 v = ((const uint4*)(hs_bf + (size_t)t * H_DIM))[tid];
    acc[0] += w * bf2f((unsigned short)(v.x & 0xffff));
    acc[1] += w * bf2f((unsigned short)(v.x >> 16));
    acc[2] += w * bf2f((unsigned short)(v.y & 0xffff));
    acc[3] += w * bf2f((unsigned short)(v.y >> 16));
    acc[4] += w * bf2f((unsigned short)(v.z & 0xffff));
    acc[5] += w * bf2f((unsigned short)(v.z >> 16));
    acc[6] += w * bf2f((unsigned short)(v.w & 0xffff));
    acc[7] += w * bf2f((unsigned short)(v.w >> 16));
  }
  float* dst = c_part + (size_t)blockIdx.x * H_DIM + tid * 8;
#pragma unroll
  for (int k = 0; k < 8; ++k) dst[k] = acc[k];
}

// ---------------- Phase 3d: reduce partials ----------------
__global__ __launch_bounds__(256) void reduce_c(
    const float* __restrict__ c_part, float* __restrict__ c) {
  const int i = blockIdx.x * 256 + threadIdx.x;
  float sum = 0.f;
  for (int b = 0; b < 64; ++b) sum += c_part[(size_t)b * H_DIM + i];
  c[i] = sum;
}

// ---------------- Phase 3e: output heads ----------------
__global__ __launch_bounds__(64) void logits_kernel(
    const float* __restrict__ W_o, const float* __restrict__ b_o,
    const float* __restrict__ W_d, const float* __restrict__ b_d,
    const float* __restrict__ c, float* __restrict__ out) {
  const int j = blockIdx.x;
  const int lane = threadIdx.x;
  const float* W; const float* bb; int jj;
  if (j < A_DIM) { W = W_o; bb = b_o; jj = j; }
  else { W = W_d; bb = b_d; jj = j - A_DIM; }
  const float4* w4 = (const float4*)(W + (size_t)jj * H_DIM);
  const float4* c4 = (const float4*)c;
  float sum = 0.f;
#pragma unroll
  for (int u = 0; u < 8; ++u) {
    float4 a = w4[lane + 64 * u];
    float4 b = c4[lane + 64 * u];
    sum += a.x * b.x + a.y * b.y + a.z * b.z + a.w * b.w;
  }
#pragma unroll
  for (int d = 32; d > 0; d >>= 1) sum += __shfl_xor(sum, d, 64);
  if (lane == 0) out[j] = sum + bb[jj];
}

extern "C" void kernel_launch(void* const* d_in, const int* in_sizes, int n_in,
                              void* d_out, int out_size, void* d_ws, size_t ws_size,
                              hipStream_t stream) {
  const float* obs  = (const float*)d_in[0];
  const float* W_ih = (const float*)d_in[1];
  const float* W_hh = (const float*)d_in[2];
  const float* b_ih = (const float*)d_in[3];
  const float* b_hh = (const float*)d_in[4];
  const float* W_o  = (const float*)d_in[5];
  const float* b_o  = (const float*)d_in[6];
  const float* W_d  = (const float*)d_in[7];
  const float* b_d  = (const float*)d_in[8];
  float* out = (float*)d_out;
  float* ws = (float*)d_ws;

  float* gxc      = ws + OFF_GXC;
  unsigned long long* htag = (unsigned long long*)(ws + OFF_HTAG);
  float* s        = ws + OFF_S;
  float* red      = ws + OFF_RED;
  float* c_part   = ws + OFF_CPART;
  float* c        = ws + OFF_C;
  unsigned short* hsbf16 = (unsigned short*)(ws + OFF_HSBF);

  // slot0 = {h=0, tag=0} for all units -> valid input for step t=0
  hipMemsetAsync(htag, 0, 2 * H_DIM * sizeof(unsigned long long), stream);

  for (int ci = 0; ci < T_DIM / CHUNK; ++ci) {
    gemm_gx<<<dim3(CHUNK / BM, G_DIM / BN), 256, 0, stream>>>(
        obs + (size_t)ci * CHUNK * O_DIM, W_ih, b_ih, gxc);
    scan_chunk<<<NBLK, 512, 0, stream>>>(
        W_hh, b_hh, gxc, htag, hsbf16, ci * CHUNK, CHUNK);
  }
  // final h (tag 8192, even) is in htag slot 0
  const unsigned long long* h_last = htag;

  const int n = T_DIM - 1;  // 8191 mid states
  attn_scores<<<(n + 3) / 4, 256, 0, stream>>>(hsbf16, h_last, s, n);
  softmax_stats<<<1, 1024, 0, stream>>>(s, n, red);
  attn_wsum<<<64, 256, 0, stream>>>(hsbf16, s, red, c_part, n);
  reduce_c<<<H_DIM / 256, 256, 0, stream>>>(c_part, c);
  logits_kernel<<<2 * A_DIM, 64, 0, stream>>>(W_o, b_o, W_d, b_d, c, out);
}

// Round 12
// 23012.033 us; speedup vs baseline: 2.3911x; 1.0050x over previous
//
#include <hip/hip_runtime.h>
#include <hip/hip_bf16.h>

#define T_DIM 8192
#define O_DIM 1024
#define H_DIM 2048
#define G_DIM 6144   // 3*H
#define A_DIM 512
#define CHUNK 512    // steps per scan launch
#define NBLK 256     // scan blocks (1 per CU; forced by dummy LDS)

// ---- workspace layout (float offsets; total ~46.7 MB, proven safe) ----
#define OFF_GXC   0ull          // CHUNK x 3H fp32            (3,145,728 f)
#define OFF_HTAG  3145728ull    // 2 x H u64 {h,tag}          (8,192 f)
#define OFF_S     3153920ull    // 8192 scores fp32
#define OFF_RED   3162112ull    // max, sum (+pad)            (16 f)
#define OFF_CPART 3162128ull    // 64 x 2048 fp32             (131,072 f)
#define OFF_C     3293200ull    // 2048 fp32
#define OFF_HSBF  3295248ull    // T x H bf16                 (8,388,608 f)

__device__ __forceinline__ float bf2f(unsigned short u) {
  return __uint_as_float(((unsigned)u) << 16);
}
__device__ __forceinline__ unsigned packbf(float a, float b) {
  return (unsigned)__bfloat16_as_ushort(__float2bfloat16(a)) |
         ((unsigned)__bfloat16_as_ushort(__float2bfloat16(b)) << 16);
}

// ---------------- Phase 1: gx chunk = obs_chunk @ W_ih^T + b_ih ----------------
#define BM 64
#define BN 64
#define BK 16
__global__ __launch_bounds__(256) void gemm_gx(
    const float* __restrict__ A,   // CHUNK x O
    const float* __restrict__ B,   // 3H x O
    const float* __restrict__ bias,
    float* __restrict__ C) {       // CHUNK x 3H
  __shared__ float As[BM][BK + 1];
  __shared__ float Bs[BN][BK + 1];
  const int bm = blockIdx.x * BM;
  const int bn = blockIdx.y * BN;
  const int tid = threadIdx.x;
  const int tr = tid / 16, tc = tid % 16;
  float acc[4][4] = {};
  for (int k0 = 0; k0 < O_DIM; k0 += BK) {
    for (int i = tid; i < BM * BK; i += 256) {
      int r = i / BK, c = i % BK;
      As[r][c] = A[(size_t)(bm + r) * O_DIM + k0 + c];
    }
    for (int i = tid; i < BN * BK; i += 256) {
      int r = i / BK, c = i % BK;
      Bs[r][c] = B[(size_t)(bn + r) * O_DIM + k0 + c];
    }
    __syncthreads();
#pragma unroll
    for (int kk = 0; kk < BK; ++kk) {
      float a[4], b[4];
#pragma unroll
      for (int i = 0; i < 4; ++i) a[i] = As[tr * 4 + i][kk];
#pragma unroll
      for (int j = 0; j < 4; ++j) b[j] = Bs[tc * 4 + j][kk];
#pragma unroll
      for (int i = 0; i < 4; ++i)
#pragma unroll
        for (int j = 0; j < 4; ++j) acc[i][j] += a[i] * b[j];
    }
    __syncthreads();
  }
#pragma unroll
  for (int i = 0; i < 4; ++i)
#pragma unroll
    for (int j = 0; j < 4; ++j) {
      int r = bm + tr * 4 + i, cc = bn + tc * 4 + j;
      C[(size_t)r * G_DIM + cc] = acc[i][j] + bias[cc];
    }
}

// unpack-and-FMA one packed-bf16 uint4 (8 cols) against two staged float4s
#define DOTQ(Q, ACC)                                                  \
  do {                                                                \
    ACC += __uint_as_float((Q).x << 16)          * ha.x               \
         + __uint_as_float((Q).x & 0xffff0000u)  * ha.y               \
         + __uint_as_float((Q).y << 16)          * ha.z               \
         + __uint_as_float((Q).y & 0xffff0000u)  * ha.w               \
         + __uint_as_float((Q).z << 16)          * hb.x               \
         + __uint_as_float((Q).z & 0xffff0000u)  * hb.y               \
         + __uint_as_float((Q).w << 16)          * hb.z               \
         + __uint_as_float((Q).w & 0xffff0000u)  * hb.w;              \
  } while (0)

// ---------------- Phase 2: persistent GRU scan -------------------------------
// r11 champion (coalesced single-line publish) with ONE change: weights held as
// 12 named uint4 = 48 VGPRs of PACKED BF16 (was: fp32 "registers" that the
// allocator remat'd into a 192KB/CU/step cache re-stream, VGPR=88, FETCH 94MB).
// 48 + ~45 live state < 128-VGPR cap at 2 waves/SIMD -> no pressure, and the
// load+cvt+pack chain is too costly to rematerialize -> expect true residency.
// h staged in LDS keeps the proven stride-16B zero-conflict ds_read_b128 form.
__global__ __launch_bounds__(512, 2) void scan_chunk(
    const float* __restrict__ W_hh,        // 3H x H fp32
    const float* __restrict__ b_hh,        // 3H
    const float* __restrict__ gxc,         // CHUNK x 3H
    unsigned long long* __restrict__ htag, // 2 x H {h,tag}
    unsigned short* __restrict__ hsbf16,   // T x H bf16
    int t0, int nsteps) {
  __shared__ char smem[98304];             // forces 1 block/CU
  float* hlbuf0 = (float*)smem;                          // H_DIM floats
  float* hlbuf1 = (float*)(smem + 8192);                 // H_DIM floats
  unsigned long long* stage = (unsigned long long*)(smem + 16384);  // 8 u64
  const int tid = threadIdx.x;
  const int lane = tid & 63;
  const int wv = tid >> 6;                 // wave 0..7
  const int blk = blockIdx.x;
  const int u = blk * 8 + wv;              // owned unit

  // ---- weights: fp32 load -> packed bf16 in 12 named uint4 (48 VGPRs) ----
  const float4* wr0 = (const float4*)(W_hh + (size_t)(0 * H_DIM + u) * H_DIM);
  const float4* wr1 = (const float4*)(W_hh + (size_t)(1 * H_DIM + u) * H_DIM);
  const float4* wr2 = (const float4*)(W_hh + (size_t)(2 * H_DIM + u) * H_DIM);
#define LOADQ(WR, J2)                                                  \
  ({ const float4 lo = (WR)[lane + 128 * (J2)];                        \
     const float4 hi = (WR)[lane + 64 + 128 * (J2)];                   \
     uint4{packbf(lo.x, lo.y), packbf(lo.z, lo.w),                     \
           packbf(hi.x, hi.y), packbf(hi.z, hi.w)}; })
  const uint4 q00 = LOADQ(wr0, 0), q01 = LOADQ(wr0, 1),
              q02 = LOADQ(wr0, 2), q03 = LOADQ(wr0, 3);
  const uint4 q10 = LOADQ(wr1, 0), q11 = LOADQ(wr1, 1),
              q12 = LOADQ(wr1, 2), q13 = LOADQ(wr1, 3);
  const uint4 q20 = LOADQ(wr2, 0), q21 = LOADQ(wr2, 1),
              q22 = LOADQ(wr2, 2), q23 = LOADQ(wr2, 3);
#undef LOADQ

  float b0 = 0.f, b1 = 0.f, b2 = 0.f;
  if (lane == 0) {
    b0 = b_hh[u]; b1 = b_hh[H_DIM + u]; b2 = b_hh[2 * H_DIM + u];
  }

  for (int tt = 0; tt < nsteps; ++tt) {
    const int t = t0 + tt;
    const unsigned long long* hin = htag + (size_t)(t & 1) * H_DIM;
    unsigned long long* hout = htag + (size_t)((t + 1) & 1) * H_DIM;
    float* hl = (t & 1) ? hlbuf1 : hlbuf0;   // double-buffered stage

    // gx for owner lane (issued early; drains at the barrier after poll)
    float gx0 = 0.f, gx1 = 0.f, gx2 = 0.f;
    if (lane == 0) {
      const float* g = gxc + (size_t)tt * G_DIM + u;
      gx0 = g[0]; gx1 = g[H_DIM]; gx2 = g[2 * H_DIM];
    }

    // ---- (A) poll-the-data: 4 u64/thread, coalesced ----
    unsigned long long v[4];
    const unsigned tgt = (unsigned)t;
    for (;;) {
      bool ok = true;
#pragma unroll
      for (int j = 0; j < 4; ++j) {
        v[j] = __hip_atomic_load(hin + tid + 512 * j,
                                 __ATOMIC_RELAXED, __HIP_MEMORY_SCOPE_AGENT);
        ok = ok && ((unsigned)v[j] >= tgt);
      }
      if (ok) break;
      __builtin_amdgcn_s_sleep(1);
    }
#pragma unroll
    for (int j = 0; j < 4; ++j)
      hl[tid + 512 * j] = __uint_as_float((unsigned)(v[j] >> 32));
    __syncthreads();   // (B) hl ready

    // ---- (C) 3 dot products off packed-bf16 register weights ----
    float a0 = 0.f, a1 = 0.f, a2 = 0.f;
    const float4* h4 = (const float4*)hl;
    {
      float4 ha, hb;
      ha = h4[lane +   0]; hb = h4[lane +  64];
      DOTQ(q00, a0); DOTQ(q10, a1); DOTQ(q20, a2);
      ha = h4[lane + 128]; hb = h4[lane + 192];
      DOTQ(q01, a0); DOTQ(q11, a1); DOTQ(q21, a2);
      ha = h4[lane + 256]; hb = h4[lane + 320];
      DOTQ(q02, a0); DOTQ(q12, a1); DOTQ(q22, a2);
      ha = h4[lane + 384]; hb = h4[lane + 448];
      DOTQ(q03, a0); DOTQ(q13, a1); DOTQ(q23, a2);
    }
#pragma unroll
    for (int d = 32; d > 0; d >>= 1) {
      a0 += __shfl_xor(a0, d, 64);
      a1 += __shfl_xor(a1, d, 64);
      a2 += __shfl_xor(a2, d, 64);
    }

    // ---- (D) gates on owner lane; stage {h,tag} in LDS ----
    float hnew = 0.f;
    if (lane == 0) {
      const float rr = 1.f / (1.f + expf(-(gx0 + a0 + b0)));
      const float zz = 1.f / (1.f + expf(-(gx1 + a1 + b1)));
      const float nn = tanhf(gx2 + rr * (a2 + b2));
      hnew = (1.f - zz) * nn + zz * hl[u];
      stage[wv] = ((unsigned long long)__float_as_uint(hnew) << 32) |
                  (unsigned long long)(unsigned)(t + 1);
    }
    __syncthreads();   // (E) stage ready

    // ---- (F) single-wave coalesced publish: one 64B line, one instruction ----
    if (tid < 8) {
      __hip_atomic_store(hout + blk * 8 + tid, stage[tid],
                         __ATOMIC_RELAXED, __HIP_MEMORY_SCOPE_AGENT);
    }
    // ---- (G) attention state (off critical path; drains under next poll) ----
    if (lane == 0) {
      hsbf16[(size_t)t * H_DIM + u] =
          (unsigned short)__bfloat16_as_ushort(__float2bfloat16(hnew));
    }
  }
}

// ---------------- Phase 3a: attention scores (bf16 h_mid, h_last from htag) ---
__global__ __launch_bounds__(256) void attn_scores(
    const unsigned short* __restrict__ hs_bf,
    const unsigned long long* __restrict__ hq,  // slot0 of htag: {h,tag=8192}
    float* __restrict__ s, int n) {
  __shared__ float hl[H_DIM];
  const int tid = threadIdx.x;
  for (int i = tid; i < H_DIM; i += 256)
    hl[i] = __uint_as_float((unsigned)(hq[i] >> 32));
  __syncthreads();
  const int wave = tid >> 6, lane = tid & 63;
  const int t = blockIdx.x * 4 + wave;
  if (t >= n) return;
  const uint4* r4 = (const uint4*)(hs_bf + (size_t)t * H_DIM);
  float sum = 0.f;
#pragma unroll
  for (int u = 0; u < 4; ++u) {
    const int idx = lane + 64 * u;
    uint4 v = r4[idx];
    const float* l = hl + idx * 8;
    sum += bf2f((unsigned short)(v.x & 0xffff)) * l[0];
    sum += bf2f((unsigned short)(v.x >> 16))    * l[1];
    sum += bf2f((unsigned short)(v.y & 0xffff)) * l[2];
    sum += bf2f((unsigned short)(v.y >> 16))    * l[3];
    sum += bf2f((unsigned short)(v.z & 0xffff)) * l[4];
    sum += bf2f((unsigned short)(v.z >> 16))    * l[5];
    sum += bf2f((unsigned short)(v.w & 0xffff)) * l[6];
    sum += bf2f((unsigned short)(v.w >> 16))    * l[7];
  }
#pragma unroll
  for (int d = 32; d > 0; d >>= 1) sum += __shfl_xor(sum, d, 64);
  if (lane == 0) s[t] = sum;
}

// ---------------- Phase 3b: softmax stats ----------------
__global__ __launch_bounds__(1024) void softmax_stats(
    const float* __restrict__ s, int n, float* __restrict__ red) {
  __shared__ float buf[1024];
  const int tid = threadIdx.x;
  float m = -3.4e38f;
  for (int i = tid; i < n; i += 1024) m = fmaxf(m, s[i]);
  buf[tid] = m;
  __syncthreads();
  for (int d = 512; d > 0; d >>= 1) {
    if (tid < d) buf[tid] = fmaxf(buf[tid], buf[tid + d]);
    __syncthreads();
  }
  const float mm = buf[0];
  __syncthreads();
  float sum = 0.f;
  for (int i = tid; i < n; i += 1024) sum += expf(s[i] - mm);
  buf[tid] = sum;
  __syncthreads();
  for (int d = 512; d > 0; d >>= 1) {
    if (tid < d) buf[tid] += buf[tid + d];
    __syncthreads();
  }
  if (tid == 0) { red[0] = mm; red[1] = buf[0]; }
}

// ---------------- Phase 3c: weighted sum partials (bf16 h_mid) ----------------
__global__ __launch_bounds__(256) void attn_wsum(
    const unsigned short* __restrict__ hs_bf, const float* __restrict__ s,
    const float* __restrict__ red, float* __restrict__ c_part, int n) {
  const int tid = threadIdx.x;
  const float m = red[0];
  const float inv = 1.f / red[1];
  const int tchunk = (n + 63) / 64;
  const int t0 = blockIdx.x * tchunk;
  const int t1 = min(t0 + tchunk, n);
  float acc[8] = {};
  for (int t = t0; t < t1; ++t) {
    const float w = expf(s[t] - m) * inv;
    const uint4 v = ((const uint4*)(hs_bf + (size_t)t * H_DIM))[tid];
    acc[0] += w * bf2f((unsigned short)(v.x & 0xffff));
    acc[1] += w * bf2f((unsigned short)(v.x >> 16));
    acc[2] += w * bf2f((unsigned short)(v.y & 0xffff));
    acc[3] += w * bf2f((unsigned short)(v.y >> 16));
    acc[4] += w * bf2f((unsigned short)(v.z & 0xffff));
    acc[5] += w * bf2f((unsigned short)(v.z >> 16));
    acc[6] += w * bf2f((unsigned short)(v.w & 0xffff));
    acc[7] += w * bf2f((unsigned short)(v.w >> 16));
  }
  float* dst = c_part + (size_t)blockIdx.x * H_DIM + tid * 8;
#pragma unroll
  for (int k = 0; k < 8; ++k) dst[k] = acc[k];
}

// ---------------- Phase 3d: reduce partials ----------------
__global__ __launch_bounds__(256) void reduce_c(
    const float* __restrict__ c_part, float* __restrict__ c) {
  const int i = blockIdx.x * 256 + threadIdx.x;
  float sum = 0.f;
  for (int b = 0; b < 64; ++b) sum += c_part[(size_t)b * H_DIM + i];
  c[i] = sum;
}

// ---------------- Phase 3e: output heads ----------------
__global__ __launch_bounds__(64) void logits_kernel(
    const float* __restrict__ W_o, const float* __restrict__ b_o,
    const float* __restrict__ W_d, const float* __restrict__ b_d,
    const float* __restrict__ c, float* __restrict__ out) {
  const int j = blockIdx.x;
  const int lane = threadIdx.x;
  const float* W; const float* bb; int jj;
  if (j < A_DIM) { W = W_o; bb = b_o; jj = j; }
  else { W = W_d; bb = b_d; jj = j - A_DIM; }
  const float4* w4 = (const float4*)(W + (size_t)jj * H_DIM);
  const float4* c4 = (const float4*)c;
  float sum = 0.f;
#pragma unroll
  for (int u = 0; u < 8; ++u) {
    float4 a = w4[lane + 64 * u];
    float4 b = c4[lane + 64 * u];
    sum += a.x * b.x + a.y * b.y + a.z * b.z + a.w * b.w;
  }
#pragma unroll
  for (int d = 32; d > 0; d >>= 1) sum += __shfl_xor(sum, d, 64);
  if (lane == 0) out[j] = sum + bb[jj];
}

extern "C" void kernel_launch(void* const* d_in, const int* in_sizes, int n_in,
                              void* d_out, int out_size, void* d_ws, size_t ws_size,
                              hipStream_t stream) {
  const float* obs  = (const float*)d_in[0];
  const float* W_ih = (const float*)d_in[1];
  const float* W_hh = (const float*)d_in[2];
  const float* b_ih = (const float*)d_in[3];
  const float* b_hh = (const float*)d_in[4];
  const float* W_o  = (const float*)d_in[5];
  const float* b_o  = (const float*)d_in[6];
  const float* W_d  = (const float*)d_in[7];
  const float* b_d  = (const float*)d_in[8];
  float* out = (float*)d_out;
  float* ws = (float*)d_ws;

  float* gxc      = ws + OFF_GXC;
  unsigned long long* htag = (unsigned long long*)(ws + OFF_HTAG);
  float* s        = ws + OFF_S;
  float* red      = ws + OFF_RED;
  float* c_part   = ws + OFF_CPART;
  float* c        = ws + OFF_C;
  unsigned short* hsbf16 = (unsigned short*)(ws + OFF_HSBF);

  // slot0 = {h=0, tag=0} for all units -> valid input for step t=0
  hipMemsetAsync(htag, 0, 2 * H_DIM * sizeof(unsigned long long), stream);

  for (int ci = 0; ci < T_DIM / CHUNK; ++ci) {
    gemm_gx<<<dim3(CHUNK / BM, G_DIM / BN), 256, 0, stream>>>(
        obs + (size_t)ci * CHUNK * O_DIM, W_ih, b_ih, gxc);
    scan_chunk<<<NBLK, 512, 0, stream>>>(
        W_hh, b_hh, gxc, htag, hsbf16, ci * CHUNK, CHUNK);
  }
  // final h (tag 8192, even) is in htag slot 0
  const unsigned long long* h_last = htag;

  const int n = T_DIM - 1;  // 8191 mid states
  attn_scores<<<(n + 3) / 4, 256, 0, stream>>>(hsbf16, h_last, s, n);
  softmax_stats<<<1, 1024, 0, stream>>>(s, n, red);
  attn_wsum<<<64, 256, 0, stream>>>(hsbf16, s, red, c_part, n);
  reduce_c<<<H_DIM / 256, 256, 0, stream>>>(c_part, c);
  logits_kernel<<<2 * A_DIM, 64, 0, stream>>>(W_o, b_o, W_d, b_d, c, out);
}